// Round 3
// baseline (526.954 us; speedup 1.0000x reference)
//
#include <hip/hip_runtime.h>
#include <hip/hip_bf16.h>

#define N_NODES 8192
#define IN_F    512
#define OUT_F   256
#define MAXNZ   512   // E[nnz/row]=164, sigma=12.7; 512 is ~27 sigma

typedef float v4f  __attribute__((ext_vector_type(4)));   // nontemporal-compatible
typedef __attribute__((ext_vector_type(8)))  short bf16x8;
typedef __attribute__((ext_vector_type(16))) float f32x16;
typedef unsigned short u16;
typedef unsigned int   u32;

__device__ __forceinline__ u16 f2bf(float f) {            // RNE fp32->bf16
  u32 u = __float_as_uint(f);
  u += 0x7fffu + ((u >> 16) & 1u);
  return (u16)(u >> 16);
}
__device__ __forceinline__ float bf2f(u16 h) {
  return __uint_as_float(((u32)h) << 16);
}

union B8 { bf16x8 v; u16 s[8]; };

__device__ __forceinline__ void split1(float f, B8& H, B8& L, int j) {
  const u16 h = f2bf(f);
  H.s[j] = h;
  L.s[j] = f2bf(f - bf2f(h));
}
__device__ __forceinline__ void split4(const float4 f, B8& H, B8& L, int off) {
  split1(f.x, H, L, off + 0);
  split1(f.y, H, L, off + 1);
  split1(f.z, H, L, off + 2);
  split1(f.w, H, L, off + 3);
}

// ---------------- Kernel 0: split-cast + transpose W -> WT_hi/WT_lo [n][k] ---
// Also zeroes s_src/s_dst (adjacent 16384 floats) -> kills the memset dispatch.
__global__ __launch_bounds__(256) void k_cast_wt(const float* __restrict__ W,
                                                 u16* __restrict__ wt_hi,
                                                 u16* __restrict__ wt_lo,
                                                 float* __restrict__ s_zero) {
  const int k = blockIdx.x;        // 512
  const int n = threadIdx.x;       // 256
  if (k < 64) s_zero[k * 256 + n] = 0.f;   // covers s_src[8192] + s_dst[8192]
  const float v = W[(size_t)k * OUT_F + n];
  const u16 h = f2bf(v);
  wt_hi[(size_t)n * IN_F + k] = h;
  wt_lo[(size_t)n * IN_F + k] = f2bf(v - bf2f(h));
}

// ---------------- Kernel 1: h = x @ W via split-bf16 MFMA, fused scores -------
// 64x64 tile, 512 blocks, 4 waves each one 32x32 C; BK=64 (8 barrier pairs).
// x read fp32, split-cast in-register; reg-staged prefetch of next K-tile.
// XCD-chunked swizzle keeps x tiles L2-resident. 3 products ~ fp32 accuracy.
// LDS rows stride 68 u16 (frag-read rows alias 2-way only = free).
// Epilogue: h_bf (bf16, 4 MB L2-resident) + fused s_src/s_dst reduction.
#define GBK 64
__global__ __launch_bounds__(256) void k_gemm_mfma(const float* __restrict__ x,
                                                   const u16* __restrict__ wt_hi,
                                                   const u16* __restrict__ wt_lo,
                                                   const float* __restrict__ a,
                                                   u16* __restrict__ h_bf,
                                                   float* __restrict__ s_src,
                                                   float* __restrict__ s_dst) {
  __shared__ u16 As_hi[64 * 68], As_lo[64 * 68], Bs_hi[64 * 68], Bs_lo[64 * 68];
  const int t    = threadIdx.x;
  const int id2  = (blockIdx.x & 7) * 64 + (blockIdx.x >> 3);   // XCD-chunked
  const int bn   = id2 & 3;            // 4 n-tiles
  const int bm   = id2 >> 2;           // 128 m-tiles
  const int m0   = bm * 64, n0 = bn * 64;
  const int lane = t & 63;
  const int w    = t >> 6;
  const int wm   = w & 1, wn = w >> 1;

  const int sm = t >> 2;               // staging row 0..63
  const int sk = (t & 3) * 16;         // staging k-offset (16 elems per thread)

  // prefetch pointers (16B-aligned)
  const float4* x4  = (const float4*)x + ((size_t)(m0 + sm) * IN_F + sk) / 4;
  const bf16x8* wh8 = (const bf16x8*)wt_hi + ((size_t)(n0 + sm) * IN_F + sk) / 8;
  const bf16x8* wl8 = (const bf16x8*)wt_lo + ((size_t)(n0 + sm) * IN_F + sk) / 8;

  // prologue: tile 0 loads
  float4 f0 = x4[0], f1 = x4[1], f2 = x4[2], f3 = x4[3];
  bf16x8 wh0 = wh8[0], wh1 = wh8[1], wl0 = wl8[0], wl1 = wl8[1];

  f32x16 acc = {};

  for (int k0 = 0; k0 < IN_F; k0 += GBK) {
    // ---- split current A regs -> hi/lo bf16; store A+B tiles to LDS ----
    B8 Ha, La, Hb, Lb;
    split4(f0, Ha, La, 0);
    split4(f1, Ha, La, 4);
    split4(f2, Hb, Lb, 0);
    split4(f3, Hb, Lb, 4);
    *(bf16x8*)&As_hi[sm * 68 + sk]     = Ha.v;
    *(bf16x8*)&As_lo[sm * 68 + sk]     = La.v;
    *(bf16x8*)&As_hi[sm * 68 + sk + 8] = Hb.v;
    *(bf16x8*)&As_lo[sm * 68 + sk + 8] = Lb.v;
    *(bf16x8*)&Bs_hi[sm * 68 + sk]     = wh0;
    *(bf16x8*)&Bs_hi[sm * 68 + sk + 8] = wh1;
    *(bf16x8*)&Bs_lo[sm * 68 + sk]     = wl0;
    *(bf16x8*)&Bs_lo[sm * 68 + sk + 8] = wl1;
    __syncthreads();

    // ---- issue next tile's global loads (in flight during MFMA phase) ----
    if (k0 + GBK < IN_F) {
      const int o4 = (k0 + GBK) >> 2;   // float4 units
      const int o8 = (k0 + GBK) >> 3;   // bf16x8 units
      f0 = x4[o4]; f1 = x4[o4 + 1]; f2 = x4[o4 + 2]; f3 = x4[o4 + 3];
      wh0 = wh8[o8]; wh1 = wh8[o8 + 1];
      wl0 = wl8[o8]; wl1 = wl8[o8 + 1];
    }

    // ---- MFMA phase (LDS reads) ----
    const int am  = wm * 32 + (lane & 31);
    const int bn_ = wn * 32 + (lane & 31);
#pragma unroll
    for (int kk = 0; kk < 4; ++kk) {
      const int ko = kk * 16 + (lane >> 5) * 8;   // A[m][k], k=(lane>>5)*8+j
      const bf16x8 ah = *(const bf16x8*)&As_hi[am * 68 + ko];
      const bf16x8 al = *(const bf16x8*)&As_lo[am * 68 + ko];
      const bf16x8 bh = *(const bf16x8*)&Bs_hi[bn_ * 68 + ko];
      const bf16x8 bl = *(const bf16x8*)&Bs_lo[bn_ * 68 + ko];
      acc = __builtin_amdgcn_mfma_f32_32x32x16_bf16(ah, bh, acc, 0, 0, 0);
      acc = __builtin_amdgcn_mfma_f32_32x32x16_bf16(al, bh, acc, 0, 0, 0);
      acc = __builtin_amdgcn_mfma_f32_32x32x16_bf16(ah, bl, acc, 0, 0, 0);
    }
    __syncthreads();
  }
  // C/D: col=lane&31, row=(reg&3)+8*(reg>>2)+4*(lane>>5)  [verified m74/m101]
  const int colg = n0 + wn * 32 + (lane & 31);
  const float asv = a[colg];            // a[:256] -> src coeffs
  const float adv = a[OUT_F + colg];    // a[256:] -> dst coeffs
#pragma unroll
  for (int r = 0; r < 16; ++r) {
    const int row = m0 + wm * 32 + (r & 3) + 8 * (r >> 2) + 4 * (lane >> 5);
    const float v = acc[r];
    h_bf[(size_t)row * OUT_F + colg] = f2bf(v);
    float vs = v * asv, vd = v * adv;
#pragma unroll
    for (int off = 1; off < 32; off <<= 1) {   // reduce over 32 cols (half-wave)
      vs += __shfl_xor(vs, off);
      vd += __shfl_xor(vd, off);
    }
    if ((lane & 31) == 0) {
      atomicAdd(&s_src[row], vs);
      atomicAdd(&s_dst[row], vd);
    }
  }
}

__device__ __forceinline__ float lrelu_exp(float v) {
  const float e = v > 0.f ? v : 0.2f * v;   // leaky_relu slope 0.2
  return __expf(e);
}

// ---------------- Kernel 3: fused softmax + mask + sparse AV ------------------
// One block per row i. adj NT loads issued FIRST (HBM stream starts under
// pass 1). OCCUPANCY VERSION: p[] is NOT kept in registers across the barrier;
// pass 2 recomputes exp (bit-identical, ~4 VALU cyc) from a re-read of s_dst
// (single 32 KB array shared by ALL blocks -> L1/L2-hot). Cross-barrier state
// drops to av[8] (~58 VGPR) -> __launch_bounds__(256,8) = 8 waves/SIMD, +60%
// blocks in flight for the HBM stream. Divergent compaction (measured faster
// than ballot). Pass-3 gathers from h_bf (4 MB bf16, per-XCD L2).
__global__ __launch_bounds__(256, 8) void k_attn(const float* __restrict__ adj,
                                                 const u16* __restrict__ h_bf,
                                                 const float* __restrict__ s_src,
                                                 const float* __restrict__ s_dst,
                                                 float* __restrict__ out_hp,
                                                 float* __restrict__ out_att) {
  __shared__ float nza[MAXNZ];     // 2 KB
  __shared__ int   nzj[MAXNZ];     // 2 KB
  __shared__ float redbuf[4];
  __shared__ int   cnt;

  const int t = threadIdx.x;
  const int i = blockIdx.x;
  if (t == 0) cnt = 0;

  // ---- issue the adj row stream immediately (hides under pass 1) ----
  const v4f* adj4 = (const v4f*)(adj + (size_t)i * N_NODES);
  v4f av[8];
#pragma unroll
  for (int c = 0; c < 8; ++c) av[c] = __builtin_nontemporal_load(adj4 + c * 256 + t);

  const float ssrc = s_src[i];

  // ---- pass 1: row sum of exp(lrelu(ssrc+s_dst)) -- p NOT kept in regs ----
  const float4* sd4 = (const float4*)s_dst;
  float lsum = 0.f;
#pragma unroll
  for (int c = 0; c < 8; ++c) {
    const float4 s = sd4[c * 256 + t];
    lsum += lrelu_exp(ssrc + s.x) + lrelu_exp(ssrc + s.y)
          + lrelu_exp(ssrc + s.z) + lrelu_exp(ssrc + s.w);
  }
#pragma unroll
  for (int off = 32; off > 0; off >>= 1) lsum += __shfl_down(lsum, off);
  if ((t & 63) == 0) redbuf[t >> 6] = lsum;
  __syncthreads();                                  // also publishes cnt=0
  const float inv = 1.0f / (redbuf[0] + redbuf[1] + redbuf[2] + redbuf[3]);

  // ---- pass 2: recompute p (bit-identical), write attention (NT), compact ----
  v4f* att4 = (v4f*)(out_att + (size_t)i * N_NODES);
#pragma unroll
  for (int c = 0; c < 8; ++c) {
    const float4 s = sd4[c * 256 + t];          // L1-hot re-read
    v4f att;
    att.x = av[c].x * (lrelu_exp(ssrc + s.x) * inv);   // av is exactly 0.0 or 1.0
    att.y = av[c].y * (lrelu_exp(ssrc + s.y) * inv);
    att.z = av[c].z * (lrelu_exp(ssrc + s.z) * inv);
    att.w = av[c].w * (lrelu_exp(ssrc + s.w) * inv);
    __builtin_nontemporal_store(att, att4 + c * 256 + t);
    const int j = (c * 256 + t) * 4;
    if (av[c].x != 0.f) { const int k = atomicAdd(&cnt, 1); if (k < MAXNZ) { nzj[k] = j + 0; nza[k] = att.x; } }
    if (av[c].y != 0.f) { const int k = atomicAdd(&cnt, 1); if (k < MAXNZ) { nzj[k] = j + 1; nza[k] = att.y; } }
    if (av[c].z != 0.f) { const int k = atomicAdd(&cnt, 1); if (k < MAXNZ) { nzj[k] = j + 2; nza[k] = att.z; } }
    if (av[c].w != 0.f) { const int k = atomicAdd(&cnt, 1); if (k < MAXNZ) { nzj[k] = j + 3; nza[k] = att.w; } }
  }
  __syncthreads();

  // ---- pass 3: h_prime[i,t] = sum att * h_bf[j,t]  (h_bf = 4 MB, L2-hot) ----
  const int n = cnt < MAXNZ ? cnt : MAXNZ;
  float acc = 0.f;
#pragma unroll 8
  for (int k = 0; k < n; ++k) {
    acc = fmaf(nza[k], bf2f(h_bf[(size_t)nzj[k] * OUT_F + t]), acc);
  }
  out_hp[(size_t)i * OUT_F + t] = acc;
}

extern "C" void kernel_launch(void* const* d_in, const int* in_sizes, int n_in,
                              void* d_out, int out_size, void* d_ws, size_t ws_size,
                              hipStream_t stream) {
  const float* x   = (const float*)d_in[0];   // [8192, 512]
  const float* adj = (const float*)d_in[1];   // [8192, 8192]
  const float* W   = (const float*)d_in[2];   // [512, 256]
  const float* a   = (const float*)d_in[3];   // [512, 1]

  float* out_hp  = (float*)d_out;                               // [8192, 256]
  float* out_att = (float*)d_out + (size_t)N_NODES * OUT_F;     // [8192, 8192]

  // workspace layout
  char* ws = (char*)d_ws;
  float* ssrc_ws = (float*)ws;                       ws += N_NODES * 4;
  float* sdst_ws = (float*)ws;                       ws += N_NODES * 4;
  u16*   wt_hi   = (u16*)ws;                         ws += (size_t)OUT_F * IN_F * 2;
  u16*   wt_lo   = (u16*)ws;                         ws += (size_t)OUT_F * IN_F * 2;
  u16*   h_bf    = (u16*)ws;                         ws += (size_t)N_NODES * OUT_F * 2;  // 4 MB

  // k_cast_wt blocks 0..63 zero s_src/s_dst (adjacent) -> no memset dispatch
  k_cast_wt<<<IN_F, OUT_F, 0, stream>>>(W, wt_hi, wt_lo, ssrc_ws);
  k_gemm_mfma<<<(N_NODES / 64) * (OUT_F / 64), 256, 0, stream>>>(
      x, wt_hi, wt_lo, a, h_bf, ssrc_ws, sdst_ws);
  k_attn<<<N_NODES, 256, 0, stream>>>(adj, h_bf, ssrc_ws, sdst_ws, out_hp, out_att);
}

// Round 4
// 519.591 us; speedup vs baseline: 1.0142x; 1.0142x over previous
//
#include <hip/hip_runtime.h>
#include <hip/hip_bf16.h>

#define N_NODES 8192
#define IN_F    512
#define OUT_F   256
#define MAXNZ   512   // E[nnz/row]=164, sigma=12.7; 512 is ~27 sigma

typedef float v4f  __attribute__((ext_vector_type(4)));   // nontemporal-compatible
typedef __attribute__((ext_vector_type(8)))  short bf16x8;
typedef __attribute__((ext_vector_type(16))) float f32x16;
typedef unsigned short u16;
typedef unsigned int   u32;

__device__ __forceinline__ u16 f2bf(float f) {            // RNE fp32->bf16
  u32 u = __float_as_uint(f);
  u += 0x7fffu + ((u >> 16) & 1u);
  return (u16)(u >> 16);
}
__device__ __forceinline__ float bf2f(u16 h) {
  return __uint_as_float(((u32)h) << 16);
}

union B8 { bf16x8 v; u16 s[8]; };

__device__ __forceinline__ void split1(float f, B8& H, B8& L, int j) {
  const u16 h = f2bf(f);
  H.s[j] = h;
  L.s[j] = f2bf(f - bf2f(h));
}
__device__ __forceinline__ void split4(const float4 f, B8& H, B8& L, int off) {
  split1(f.x, H, L, off + 0);
  split1(f.y, H, L, off + 1);
  split1(f.z, H, L, off + 2);
  split1(f.w, H, L, off + 3);
}

// ---------------- Kernel 0: split-cast + transpose W -> WT_hi/WT_lo [n][k] ---
// Also zeroes s_src/s_dst (adjacent 16384 floats) -> kills the memset dispatch.
__global__ __launch_bounds__(256) void k_cast_wt(const float* __restrict__ W,
                                                 u16* __restrict__ wt_hi,
                                                 u16* __restrict__ wt_lo,
                                                 float* __restrict__ s_zero) {
  const int k = blockIdx.x;        // 512
  const int n = threadIdx.x;       // 256
  if (k < 64) s_zero[k * 256 + n] = 0.f;   // covers s_src[8192] + s_dst[8192]
  const float v = W[(size_t)k * OUT_F + n];
  const u16 h = f2bf(v);
  wt_hi[(size_t)n * IN_F + k] = h;
  wt_lo[(size_t)n * IN_F + k] = f2bf(v - bf2f(h));
}

// ---------------- Kernel 1: h = x @ W via split-bf16 MFMA, fused scores -------
// 64x64 tile, 512 blocks, 4 waves each one 32x32 C; BK=64 (8 barrier pairs).
// x read fp32, split-cast in-register; reg-staged prefetch of next K-tile.
// XCD-chunked swizzle keeps x tiles L2-resident. 3 products ~ fp32 accuracy.
// LDS rows stride 68 u16 (frag-read rows alias 2-way only = free).
// Epilogue: h_bf (bf16, 4 MB L2-resident) + fused s_src/s_dst reduction.
#define GBK 64
__global__ __launch_bounds__(256) void k_gemm_mfma(const float* __restrict__ x,
                                                   const u16* __restrict__ wt_hi,
                                                   const u16* __restrict__ wt_lo,
                                                   const float* __restrict__ a,
                                                   u16* __restrict__ h_bf,
                                                   float* __restrict__ s_src,
                                                   float* __restrict__ s_dst) {
  __shared__ u16 As_hi[64 * 68], As_lo[64 * 68], Bs_hi[64 * 68], Bs_lo[64 * 68];
  const int t    = threadIdx.x;
  const int id2  = (blockIdx.x & 7) * 64 + (blockIdx.x >> 3);   // XCD-chunked
  const int bn   = id2 & 3;            // 4 n-tiles
  const int bm   = id2 >> 2;           // 128 m-tiles
  const int m0   = bm * 64, n0 = bn * 64;
  const int lane = t & 63;
  const int w    = t >> 6;
  const int wm   = w & 1, wn = w >> 1;

  const int sm = t >> 2;               // staging row 0..63
  const int sk = (t & 3) * 16;         // staging k-offset (16 elems per thread)

  // prefetch pointers (16B-aligned)
  const float4* x4  = (const float4*)x + ((size_t)(m0 + sm) * IN_F + sk) / 4;
  const bf16x8* wh8 = (const bf16x8*)wt_hi + ((size_t)(n0 + sm) * IN_F + sk) / 8;
  const bf16x8* wl8 = (const bf16x8*)wt_lo + ((size_t)(n0 + sm) * IN_F + sk) / 8;

  // prologue: tile 0 loads
  float4 f0 = x4[0], f1 = x4[1], f2 = x4[2], f3 = x4[3];
  bf16x8 wh0 = wh8[0], wh1 = wh8[1], wl0 = wl8[0], wl1 = wl8[1];

  f32x16 acc = {};

  for (int k0 = 0; k0 < IN_F; k0 += GBK) {
    // ---- split current A regs -> hi/lo bf16; store A+B tiles to LDS ----
    B8 Ha, La, Hb, Lb;
    split4(f0, Ha, La, 0);
    split4(f1, Ha, La, 4);
    split4(f2, Hb, Lb, 0);
    split4(f3, Hb, Lb, 4);
    *(bf16x8*)&As_hi[sm * 68 + sk]     = Ha.v;
    *(bf16x8*)&As_lo[sm * 68 + sk]     = La.v;
    *(bf16x8*)&As_hi[sm * 68 + sk + 8] = Hb.v;
    *(bf16x8*)&As_lo[sm * 68 + sk + 8] = Lb.v;
    *(bf16x8*)&Bs_hi[sm * 68 + sk]     = wh0;
    *(bf16x8*)&Bs_hi[sm * 68 + sk + 8] = wh1;
    *(bf16x8*)&Bs_lo[sm * 68 + sk]     = wl0;
    *(bf16x8*)&Bs_lo[sm * 68 + sk + 8] = wl1;
    __syncthreads();

    // ---- issue next tile's global loads (in flight during MFMA phase) ----
    if (k0 + GBK < IN_F) {
      const int o4 = (k0 + GBK) >> 2;   // float4 units
      const int o8 = (k0 + GBK) >> 3;   // bf16x8 units
      f0 = x4[o4]; f1 = x4[o4 + 1]; f2 = x4[o4 + 2]; f3 = x4[o4 + 3];
      wh0 = wh8[o8]; wh1 = wh8[o8 + 1];
      wl0 = wl8[o8]; wl1 = wl8[o8 + 1];
    }

    // ---- MFMA phase (LDS reads) ----
    const int am  = wm * 32 + (lane & 31);
    const int bn_ = wn * 32 + (lane & 31);
#pragma unroll
    for (int kk = 0; kk < 4; ++kk) {
      const int ko = kk * 16 + (lane >> 5) * 8;   // A[m][k], k=(lane>>5)*8+j
      const bf16x8 ah = *(const bf16x8*)&As_hi[am * 68 + ko];
      const bf16x8 al = *(const bf16x8*)&As_lo[am * 68 + ko];
      const bf16x8 bh = *(const bf16x8*)&Bs_hi[bn_ * 68 + ko];
      const bf16x8 bl = *(const bf16x8*)&Bs_lo[bn_ * 68 + ko];
      acc = __builtin_amdgcn_mfma_f32_32x32x16_bf16(ah, bh, acc, 0, 0, 0);
      acc = __builtin_amdgcn_mfma_f32_32x32x16_bf16(al, bh, acc, 0, 0, 0);
      acc = __builtin_amdgcn_mfma_f32_32x32x16_bf16(ah, bl, acc, 0, 0, 0);
    }
    __syncthreads();
  }
  // C/D: col=lane&31, row=(reg&3)+8*(reg>>2)+4*(lane>>5)  [verified m74/m101]
  const int colg = n0 + wn * 32 + (lane & 31);
  const float asv = a[colg];            // a[:256] -> src coeffs
  const float adv = a[OUT_F + colg];    // a[256:] -> dst coeffs
#pragma unroll
  for (int r = 0; r < 16; ++r) {
    const int row = m0 + wm * 32 + (r & 3) + 8 * (r >> 2) + 4 * (lane >> 5);
    const float v = acc[r];
    h_bf[(size_t)row * OUT_F + colg] = f2bf(v);
    float vs = v * asv, vd = v * adv;
#pragma unroll
    for (int off = 1; off < 32; off <<= 1) {   // reduce over 32 cols (half-wave)
      vs += __shfl_xor(vs, off);
      vd += __shfl_xor(vd, off);
    }
    if ((lane & 31) == 0) {
      atomicAdd(&s_src[row], vs);
      atomicAdd(&s_dst[row], vd);
    }
  }
}

__device__ __forceinline__ float lrelu_exp(float v) {
  const float e = v > 0.f ? v : 0.2f * v;   // leaky_relu slope 0.2
  return __expf(e);
}

// ---------------- Kernel 3: fused softmax + mask + sparse AV ------------------
// One block per row i. adj NT loads issued FIRST (stream starts immediately;
// pass-1 exp work hides their latency). BIT-PACKED adj: av in {0.0,1.0} ->
// one 32-bit mask per thread. Cross-barrier state = {mask, ssrc, inv} (~3
// VGPRs vs 64 before). Pass 2 recomputes p from L1-hot s_dst (bit-identical).
// Peak pressure ~60 VGPR -> natural 8 waves/SIMD (2x blocks/CU vs p[]+av[]
// version) WITHOUT a launch-bounds cap (round-3 cap caused ~400 MB of scratch
// spills, +26 us). Divergent compaction. Pass-3 gathers from h_bf (4 MB, L2).
__global__ __launch_bounds__(256) void k_attn(const float* __restrict__ adj,
                                              const u16* __restrict__ h_bf,
                                              const float* __restrict__ s_src,
                                              const float* __restrict__ s_dst,
                                              float* __restrict__ out_hp,
                                              float* __restrict__ out_att) {
  __shared__ float nza[MAXNZ];     // 2 KB
  __shared__ int   nzj[MAXNZ];     // 2 KB
  __shared__ float redbuf[4];
  __shared__ int   cnt;

  const int t = threadIdx.x;
  const int i = blockIdx.x;
  if (t == 0) cnt = 0;

  // ---- issue the adj row stream immediately (hides under pass 1) ----
  const v4f* adj4 = (const v4f*)(adj + (size_t)i * N_NODES);
  v4f av[8];
#pragma unroll
  for (int c = 0; c < 8; ++c) av[c] = __builtin_nontemporal_load(adj4 + c * 256 + t);

  const float ssrc = s_src[i];

  // ---- pass 1: row sum of exp(lrelu(ssrc+s_dst)) (overlaps adj latency) ----
  const float4* sd4 = (const float4*)s_dst;
  float lsum = 0.f;
#pragma unroll
  for (int c = 0; c < 8; ++c) {
    const float4 s = sd4[c * 256 + t];
    lsum += lrelu_exp(ssrc + s.x) + lrelu_exp(ssrc + s.y)
          + lrelu_exp(ssrc + s.z) + lrelu_exp(ssrc + s.w);
  }

  // ---- pack adj row to 32 bits: av[8] (32 VGPRs) dies here ----
  u32 mask = 0;
#pragma unroll
  for (int c = 0; c < 8; ++c) {
    mask |= (av[c].x != 0.f ? 1u : 0u) << (4 * c + 0);
    mask |= (av[c].y != 0.f ? 1u : 0u) << (4 * c + 1);
    mask |= (av[c].z != 0.f ? 1u : 0u) << (4 * c + 2);
    mask |= (av[c].w != 0.f ? 1u : 0u) << (4 * c + 3);
  }

#pragma unroll
  for (int off = 32; off > 0; off >>= 1) lsum += __shfl_down(lsum, off);
  if ((t & 63) == 0) redbuf[t >> 6] = lsum;
  __syncthreads();                                  // also publishes cnt=0
  const float inv = 1.0f / (redbuf[0] + redbuf[1] + redbuf[2] + redbuf[3]);

  // ---- pass 2: recompute p (bit-identical), mask-select, NT store, compact ----
  v4f* att4 = (v4f*)(out_att + (size_t)i * N_NODES);
#pragma unroll
  for (int c = 0; c < 8; ++c) {
    const float4 s = sd4[c * 256 + t];          // L1-hot re-read
    v4f att;
    att.x = (mask >> (4 * c + 0)) & 1u ? lrelu_exp(ssrc + s.x) * inv : 0.f;
    att.y = (mask >> (4 * c + 1)) & 1u ? lrelu_exp(ssrc + s.y) * inv : 0.f;
    att.z = (mask >> (4 * c + 2)) & 1u ? lrelu_exp(ssrc + s.z) * inv : 0.f;
    att.w = (mask >> (4 * c + 3)) & 1u ? lrelu_exp(ssrc + s.w) * inv : 0.f;
    __builtin_nontemporal_store(att, att4 + c * 256 + t);
    const int j = (c * 256 + t) * 4;
    if ((mask >> (4 * c + 0)) & 1u) { const int k = atomicAdd(&cnt, 1); if (k < MAXNZ) { nzj[k] = j + 0; nza[k] = att.x; } }
    if ((mask >> (4 * c + 1)) & 1u) { const int k = atomicAdd(&cnt, 1); if (k < MAXNZ) { nzj[k] = j + 1; nza[k] = att.y; } }
    if ((mask >> (4 * c + 2)) & 1u) { const int k = atomicAdd(&cnt, 1); if (k < MAXNZ) { nzj[k] = j + 2; nza[k] = att.z; } }
    if ((mask >> (4 * c + 3)) & 1u) { const int k = atomicAdd(&cnt, 1); if (k < MAXNZ) { nzj[k] = j + 3; nza[k] = att.w; } }
  }
  __syncthreads();

  // ---- pass 3: h_prime[i,t] = sum att * h_bf[j,t]  (h_bf = 4 MB, L2-hot) ----
  const int n = cnt < MAXNZ ? cnt : MAXNZ;
  float acc = 0.f;
#pragma unroll 8
  for (int k = 0; k < n; ++k) {
    acc = fmaf(nza[k], bf2f(h_bf[(size_t)nzj[k] * OUT_F + t]), acc);
  }
  out_hp[(size_t)i * OUT_F + t] = acc;
}

extern "C" void kernel_launch(void* const* d_in, const int* in_sizes, int n_in,
                              void* d_out, int out_size, void* d_ws, size_t ws_size,
                              hipStream_t stream) {
  const float* x   = (const float*)d_in[0];   // [8192, 512]
  const float* adj = (const float*)d_in[1];   // [8192, 8192]
  const float* W   = (const float*)d_in[2];   // [512, 256]
  const float* a   = (const float*)d_in[3];   // [512, 1]

  float* out_hp  = (float*)d_out;                               // [8192, 256]
  float* out_att = (float*)d_out + (size_t)N_NODES * OUT_F;     // [8192, 8192]

  // workspace layout
  char* ws = (char*)d_ws;
  float* ssrc_ws = (float*)ws;                       ws += N_NODES * 4;
  float* sdst_ws = (float*)ws;                       ws += N_NODES * 4;
  u16*   wt_hi   = (u16*)ws;                         ws += (size_t)OUT_F * IN_F * 2;
  u16*   wt_lo   = (u16*)ws;                         ws += (size_t)OUT_F * IN_F * 2;
  u16*   h_bf    = (u16*)ws;                         ws += (size_t)N_NODES * OUT_F * 2;  // 4 MB

  // k_cast_wt blocks 0..63 zero s_src/s_dst (adjacent) -> no memset dispatch
  k_cast_wt<<<IN_F, OUT_F, 0, stream>>>(W, wt_hi, wt_lo, ssrc_ws);
  k_gemm_mfma<<<(N_NODES / 64) * (OUT_F / 64), 256, 0, stream>>>(
      x, wt_hi, wt_lo, a, h_bf, ssrc_ws, sdst_ws);
  k_attn<<<N_NODES, 256, 0, stream>>>(adj, h_bf, ssrc_ws, sdst_ws, out_hp, out_att);
}

// Round 5
// 498.069 us; speedup vs baseline: 1.0580x; 1.0432x over previous
//
#include <hip/hip_runtime.h>
#include <hip/hip_bf16.h>

#define N_NODES 8192
#define IN_F    512
#define OUT_F   256
#define MAXNZ   512   // E[nnz/row]=164, sigma=12.7; 512 is ~27 sigma

typedef float v4f  __attribute__((ext_vector_type(4)));   // nontemporal-compatible
typedef __attribute__((ext_vector_type(8)))  short bf16x8;
typedef __attribute__((ext_vector_type(16))) float f32x16;
typedef unsigned short u16;
typedef unsigned int   u32;

__device__ __forceinline__ u16 f2bf(float f) {            // RNE fp32->bf16
  u32 u = __float_as_uint(f);
  u += 0x7fffu + ((u >> 16) & 1u);
  return (u16)(u >> 16);
}
__device__ __forceinline__ float bf2f(u16 h) {
  return __uint_as_float(((u32)h) << 16);
}

union B8 { bf16x8 v; u16 s[8]; };

__device__ __forceinline__ void split1(float f, B8& H, B8& L, int j) {
  const u16 h = f2bf(f);
  H.s[j] = h;
  L.s[j] = f2bf(f - bf2f(h));
}
__device__ __forceinline__ void split4(const float4 f, B8& H, B8& L, int off) {
  split1(f.x, H, L, off + 0);
  split1(f.y, H, L, off + 1);
  split1(f.z, H, L, off + 2);
  split1(f.w, H, L, off + 3);
}

// ---------------- Kernel 0: split-cast + transpose W -> WT_hi/WT_lo [n][k] ---
// Also zeroes s_src/s_dst (adjacent 16384 floats) -> kills the memset dispatch.
__global__ __launch_bounds__(256) void k_cast_wt(const float* __restrict__ W,
                                                 u16* __restrict__ wt_hi,
                                                 u16* __restrict__ wt_lo,
                                                 float* __restrict__ s_zero) {
  const int k = blockIdx.x;        // 512
  const int n = threadIdx.x;       // 256
  if (k < 64) s_zero[k * 256 + n] = 0.f;   // covers s_src[8192] + s_dst[8192]
  const float v = W[(size_t)k * OUT_F + n];
  const u16 h = f2bf(v);
  wt_hi[(size_t)n * IN_F + k] = h;
  wt_lo[(size_t)n * IN_F + k] = f2bf(v - bf2f(h));
}

// ---------------- Kernel 1: h = x @ W via split-bf16 MFMA, fused scores -------
// 64x64 tile, 512 blocks, 4 waves each one 32x32 C; BK=64 (8 barrier pairs).
// x read fp32, split-cast in-register; reg-staged prefetch of next K-tile.
// XCD-chunked swizzle keeps x tiles L2-resident. 3 products ~ fp32 accuracy.
// LDS rows stride 68 u16 (frag-read rows alias 2-way only = free).
// Epilogue: h_bf (bf16, 4 MB L2-resident) + fused s_src/s_dst reduction.
#define GBK 64
__global__ __launch_bounds__(256) void k_gemm_mfma(const float* __restrict__ x,
                                                   const u16* __restrict__ wt_hi,
                                                   const u16* __restrict__ wt_lo,
                                                   const float* __restrict__ a,
                                                   u16* __restrict__ h_bf,
                                                   float* __restrict__ s_src,
                                                   float* __restrict__ s_dst) {
  __shared__ u16 As_hi[64 * 68], As_lo[64 * 68], Bs_hi[64 * 68], Bs_lo[64 * 68];
  const int t    = threadIdx.x;
  const int id2  = (blockIdx.x & 7) * 64 + (blockIdx.x >> 3);   // XCD-chunked
  const int bn   = id2 & 3;            // 4 n-tiles
  const int bm   = id2 >> 2;           // 128 m-tiles
  const int m0   = bm * 64, n0 = bn * 64;
  const int lane = t & 63;
  const int w    = t >> 6;
  const int wm   = w & 1, wn = w >> 1;

  const int sm = t >> 2;               // staging row 0..63
  const int sk = (t & 3) * 16;         // staging k-offset (16 elems per thread)

  // prefetch pointers (16B-aligned)
  const float4* x4  = (const float4*)x + ((size_t)(m0 + sm) * IN_F + sk) / 4;
  const bf16x8* wh8 = (const bf16x8*)wt_hi + ((size_t)(n0 + sm) * IN_F + sk) / 8;
  const bf16x8* wl8 = (const bf16x8*)wt_lo + ((size_t)(n0 + sm) * IN_F + sk) / 8;

  // prologue: tile 0 loads
  float4 f0 = x4[0], f1 = x4[1], f2 = x4[2], f3 = x4[3];
  bf16x8 wh0 = wh8[0], wh1 = wh8[1], wl0 = wl8[0], wl1 = wl8[1];

  f32x16 acc = {};

  for (int k0 = 0; k0 < IN_F; k0 += GBK) {
    // ---- split current A regs -> hi/lo bf16; store A+B tiles to LDS ----
    B8 Ha, La, Hb, Lb;
    split4(f0, Ha, La, 0);
    split4(f1, Ha, La, 4);
    split4(f2, Hb, Lb, 0);
    split4(f3, Hb, Lb, 4);
    *(bf16x8*)&As_hi[sm * 68 + sk]     = Ha.v;
    *(bf16x8*)&As_lo[sm * 68 + sk]     = La.v;
    *(bf16x8*)&As_hi[sm * 68 + sk + 8] = Hb.v;
    *(bf16x8*)&As_lo[sm * 68 + sk + 8] = Lb.v;
    *(bf16x8*)&Bs_hi[sm * 68 + sk]     = wh0;
    *(bf16x8*)&Bs_hi[sm * 68 + sk + 8] = wh1;
    *(bf16x8*)&Bs_lo[sm * 68 + sk]     = wl0;
    *(bf16x8*)&Bs_lo[sm * 68 + sk + 8] = wl1;
    __syncthreads();

    // ---- issue next tile's global loads (in flight during MFMA phase) ----
    if (k0 + GBK < IN_F) {
      const int o4 = (k0 + GBK) >> 2;   // float4 units
      const int o8 = (k0 + GBK) >> 3;   // bf16x8 units
      f0 = x4[o4]; f1 = x4[o4 + 1]; f2 = x4[o4 + 2]; f3 = x4[o4 + 3];
      wh0 = wh8[o8]; wh1 = wh8[o8 + 1];
      wl0 = wl8[o8]; wl1 = wl8[o8 + 1];
    }

    // ---- MFMA phase (LDS reads) ----
    const int am  = wm * 32 + (lane & 31);
    const int bn_ = wn * 32 + (lane & 31);
#pragma unroll
    for (int kk = 0; kk < 4; ++kk) {
      const int ko = kk * 16 + (lane >> 5) * 8;   // A[m][k], k=(lane>>5)*8+j
      const bf16x8 ah = *(const bf16x8*)&As_hi[am * 68 + ko];
      const bf16x8 al = *(const bf16x8*)&As_lo[am * 68 + ko];
      const bf16x8 bh = *(const bf16x8*)&Bs_hi[bn_ * 68 + ko];
      const bf16x8 bl = *(const bf16x8*)&Bs_lo[bn_ * 68 + ko];
      acc = __builtin_amdgcn_mfma_f32_32x32x16_bf16(ah, bh, acc, 0, 0, 0);
      acc = __builtin_amdgcn_mfma_f32_32x32x16_bf16(al, bh, acc, 0, 0, 0);
      acc = __builtin_amdgcn_mfma_f32_32x32x16_bf16(ah, bl, acc, 0, 0, 0);
    }
    __syncthreads();
  }
  // C/D: col=lane&31, row=(reg&3)+8*(reg>>2)+4*(lane>>5)  [verified m74/m101]
  const int colg = n0 + wn * 32 + (lane & 31);
  const float asv = a[colg];            // a[:256] -> src coeffs
  const float adv = a[OUT_F + colg];    // a[256:] -> dst coeffs
#pragma unroll
  for (int r = 0; r < 16; ++r) {
    const int row = m0 + wm * 32 + (r & 3) + 8 * (r >> 2) + 4 * (lane >> 5);
    const float v = acc[r];
    h_bf[(size_t)row * OUT_F + colg] = f2bf(v);
    float vs = v * asv, vd = v * adv;
#pragma unroll
    for (int off = 1; off < 32; off <<= 1) {   // reduce over 32 cols (half-wave)
      vs += __shfl_xor(vs, off);
      vd += __shfl_xor(vd, off);
    }
    if ((lane & 31) == 0) {
      atomicAdd(&s_src[row], vs);
      atomicAdd(&s_dst[row], vd);
    }
  }
}

__device__ __forceinline__ float lrelu_exp(float v) {
  const float e = v > 0.f ? v : 0.2f * v;   // leaky_relu slope 0.2
  return __expf(e);
}

// ---------------- Kernel 3: fused softmax + mask + sparse AV ------------------
// One block per row i. SINGLE-BARRIER design combining the r2 and r4 lessons:
//  pass 1: adj NT loads in flight; p[8] computed (KEPT in regs -> pass-2 store
//          stream is fed by ready values, r2's win); av consumed chunk-by-chunk
//          into a 1-bit mask + COMPACTION (nza = raw p; inv applied once at the
//          end: out_hp = acc*inv, pure reassociation). av[] dies in pass 1 ->
//          peak state ~= p[8] + transient av -> no spill, higher occupancy.
//  barrier: publishes redbuf AND compaction (the pass2->pass3 barrier is GONE:
//          pass 3's L2 gathers overlap the pass-2 NT store drain).
//  pass 2: PURE store stream: cndmask(p*inv, 0) + NT store (att bits identical
//          to r2: p*inv or exact 0).
__global__ __launch_bounds__(256) void k_attn(const float* __restrict__ adj,
                                              const u16* __restrict__ h_bf,
                                              const float* __restrict__ s_src,
                                              const float* __restrict__ s_dst,
                                              float* __restrict__ out_hp,
                                              float* __restrict__ out_att) {
  __shared__ float nza[MAXNZ];     // 2 KB (raw p values of nonzeros)
  __shared__ int   nzj[MAXNZ];     // 2 KB
  __shared__ float redbuf[4];
  __shared__ int   cnt;

  const int t = threadIdx.x;
  const int i = blockIdx.x;
  if (t == 0) cnt = 0;
  __syncthreads();                 // publish cnt=0 (free: nothing in flight)

  // ---- issue the adj row stream (consumed chunk-by-chunk below) ----
  const v4f* adj4 = (const v4f*)(adj + (size_t)i * N_NODES);
  v4f av[8];
#pragma unroll
  for (int c = 0; c < 8; ++c) av[c] = __builtin_nontemporal_load(adj4 + c * 256 + t);

  const float ssrc = s_src[i];
  const float4* sd4 = (const float4*)s_dst;

  // ---- pass 1: p[8] (kept), lsum, mask, compaction (under load shadow) ----
  float4 p[8];
  float lsum = 0.f;
  u32 mask = 0;
#pragma unroll
  for (int c = 0; c < 8; ++c) {
    const float4 s = sd4[c * 256 + t];
    p[c].x = lrelu_exp(ssrc + s.x);
    p[c].y = lrelu_exp(ssrc + s.y);
    p[c].z = lrelu_exp(ssrc + s.z);
    p[c].w = lrelu_exp(ssrc + s.w);
    lsum += p[c].x + p[c].y + p[c].z + p[c].w;
    const int j = (c * 256 + t) * 4;
    if (av[c].x != 0.f) { mask |= 1u << (4 * c + 0); const int k = atomicAdd(&cnt, 1); if (k < MAXNZ) { nzj[k] = j + 0; nza[k] = p[c].x; } }
    if (av[c].y != 0.f) { mask |= 1u << (4 * c + 1); const int k = atomicAdd(&cnt, 1); if (k < MAXNZ) { nzj[k] = j + 1; nza[k] = p[c].y; } }
    if (av[c].z != 0.f) { mask |= 1u << (4 * c + 2); const int k = atomicAdd(&cnt, 1); if (k < MAXNZ) { nzj[k] = j + 2; nza[k] = p[c].z; } }
    if (av[c].w != 0.f) { mask |= 1u << (4 * c + 3); const int k = atomicAdd(&cnt, 1); if (k < MAXNZ) { nzj[k] = j + 3; nza[k] = p[c].w; } }
  }

#pragma unroll
  for (int off = 32; off > 0; off >>= 1) lsum += __shfl_down(lsum, off);
  if ((t & 63) == 0) redbuf[t >> 6] = lsum;
  __syncthreads();                 // publishes redbuf AND compaction (only barrier)
  const float inv = 1.0f / (redbuf[0] + redbuf[1] + redbuf[2] + redbuf[3]);

  // ---- pass 2: pure NT store stream (att = p*inv or exact 0) ----
  v4f* att4 = (v4f*)(out_att + (size_t)i * N_NODES);
#pragma unroll
  for (int c = 0; c < 8; ++c) {
    v4f att;
    att.x = (mask >> (4 * c + 0)) & 1u ? p[c].x * inv : 0.f;
    att.y = (mask >> (4 * c + 1)) & 1u ? p[c].y * inv : 0.f;
    att.z = (mask >> (4 * c + 2)) & 1u ? p[c].z * inv : 0.f;
    att.w = (mask >> (4 * c + 3)) & 1u ? p[c].w * inv : 0.f;
    __builtin_nontemporal_store(att, att4 + c * 256 + t);
  }

  // ---- pass 3 (no barrier: compaction done in pass 1; overlaps store drain) ----
  const int n = cnt < MAXNZ ? cnt : MAXNZ;
  float acc = 0.f;
#pragma unroll 8
  for (int k = 0; k < n; ++k) {
    acc = fmaf(nza[k], bf2f(h_bf[(size_t)nzj[k] * OUT_F + t]), acc);
  }
  out_hp[(size_t)i * OUT_F + t] = acc * inv;
}

extern "C" void kernel_launch(void* const* d_in, const int* in_sizes, int n_in,
                              void* d_out, int out_size, void* d_ws, size_t ws_size,
                              hipStream_t stream) {
  const float* x   = (const float*)d_in[0];   // [8192, 512]
  const float* adj = (const float*)d_in[1];   // [8192, 8192]
  const float* W   = (const float*)d_in[2];   // [512, 256]
  const float* a   = (const float*)d_in[3];   // [512, 1]

  float* out_hp  = (float*)d_out;                               // [8192, 256]
  float* out_att = (float*)d_out + (size_t)N_NODES * OUT_F;     // [8192, 8192]

  // workspace layout
  char* ws = (char*)d_ws;
  float* ssrc_ws = (float*)ws;                       ws += N_NODES * 4;
  float* sdst_ws = (float*)ws;                       ws += N_NODES * 4;
  u16*   wt_hi   = (u16*)ws;                         ws += (size_t)OUT_F * IN_F * 2;
  u16*   wt_lo   = (u16*)ws;                         ws += (size_t)OUT_F * IN_F * 2;
  u16*   h_bf    = (u16*)ws;                         ws += (size_t)N_NODES * OUT_F * 2;  // 4 MB

  // k_cast_wt blocks 0..63 zero s_src/s_dst (adjacent) -> no memset dispatch
  k_cast_wt<<<IN_F, OUT_F, 0, stream>>>(W, wt_hi, wt_lo, ssrc_ws);
  k_gemm_mfma<<<(N_NODES / 64) * (OUT_F / 64), 256, 0, stream>>>(
      x, wt_hi, wt_lo, a, h_bf, ssrc_ws, sdst_ws);
  k_attn<<<N_NODES, 256, 0, stream>>>(adj, h_bf, ssrc_ws, sdst_ws, out_hp, out_att);
}